// Round 1
// baseline (321.699 us; speedup 1.0000x reference)
//
#include <hip/hip_runtime.h>
#include <hip/hip_bf16.h>

// Problem constants
constexpr int BB = 4;
constexpr int TT = 1024;
constexpr int DD = 512;
constexpr int PP = 64;
constexpr int MM = 256;

__device__ __forceinline__ float fast_tanh(float x) {
    // tanh(x) = 1 - 2/(exp(2x)+1); v_exp + v_rcp, rel err ~1e-6.
    // Saturates correctly: x->+inf: exp->inf, rcp->0 -> 1; x->-inf: exp->0 -> -1.
    float e = __expf(2.0f * x);
    return 1.0f - 2.0f * __builtin_amdgcn_rcpf(e + 1.0f);
}

// Kernel 1: w1h = inputs@W1 + b1 ; w2h = inputs@W2 + b2   (rows = B*T = 4096, cols = P = 64)
__global__ __launch_bounds__(256) void proj_kernel(
    const float* __restrict__ x, const float* __restrict__ W1, const float* __restrict__ b1,
    const float* __restrict__ W2, const float* __restrict__ b2,
    float* __restrict__ w1h, float* __restrict__ w2h) {
    int tid = threadIdx.x;
    int p = tid & 63;
    int row = (blockIdx.x << 2) + (tid >> 6);   // 0..4095
    const float* xr = x + (size_t)row * DD;
    float a1 = b1[p], a2 = b2[p];
    #pragma unroll 4
    for (int d = 0; d < DD; d++) {
        float xv = xr[d];
        a1 = fmaf(xv, W1[d * PP + p], a1);
        a2 = fmaf(xv, W2[d * PP + p], a2);
    }
    w1h[(size_t)row * PP + p] = a1;
    w2h[(size_t)row * PP + p] = a2;
}

// Kernel 2: w3e = ec@W3 + b3   (B x P = 4 x 64 outputs)
__global__ __launch_bounds__(256) void ec_proj_kernel(
    const float* __restrict__ ec, const float* __restrict__ W3,
    const float* __restrict__ b3, float* __restrict__ w3e) {
    int tid = threadIdx.x;            // 256 threads, one per (b,p)
    int b = tid >> 6, p = tid & 63;
    float a = b3[p];
    const float* e = ec + (size_t)b * MM;
    #pragma unroll 4
    for (int m = 0; m < MM; m++) a = fmaf(e[m], W3[m * PP + p], a);
    w3e[b * PP + p] = a;
}

// Kernel 3: one block per (b,t). Compute 1024 scores, softmax, write at row.
__global__ __launch_bounds__(256) void scores_kernel(
    const float* __restrict__ w1h, const float* __restrict__ w2h,
    const float* __restrict__ w3e, const float* __restrict__ wa_w,
    const float* __restrict__ wa_b, float* __restrict__ at) {
    __shared__ float h1s[PP];
    __shared__ float waws[PP];
    __shared__ float red[4];
    int tid = threadIdx.x;
    int bt = blockIdx.x;              // b*T + t
    int b = bt >> 10;
    if (tid < PP) {
        h1s[tid] = w1h[(size_t)bt * PP + tid] + w3e[b * PP + tid];
        waws[tid] = wa_w[tid];
    }
    __syncthreads();
    float wab = wa_b[0];

    float sc[4];
    float lmax = -1e30f;
    #pragma unroll
    for (int k = 0; k < 4; k++) {
        int u = (k << 8) + tid;
        const float4* wrow = (const float4*)(w2h + ((size_t)(b << 10) + u) * PP);
        float acc = wab;
        #pragma unroll
        for (int q = 0; q < 16; q++) {
            float4 w = wrow[q];
            float4 h = *(const float4*)&h1s[q << 2];
            float4 ww = *(const float4*)&waws[q << 2];
            acc = fmaf(fast_tanh(h.x + w.x), ww.x, acc);
            acc = fmaf(fast_tanh(h.y + w.y), ww.y, acc);
            acc = fmaf(fast_tanh(h.z + w.z), ww.z, acc);
            acc = fmaf(fast_tanh(h.w + w.w), ww.w, acc);
        }
        sc[k] = acc;
        lmax = fmaxf(lmax, acc);
    }
    // block max
    #pragma unroll
    for (int off = 32; off > 0; off >>= 1) lmax = fmaxf(lmax, __shfl_xor(lmax, off, 64));
    if ((tid & 63) == 0) red[tid >> 6] = lmax;
    __syncthreads();
    float mx = fmaxf(fmaxf(red[0], red[1]), fmaxf(red[2], red[3]));

    float lsum = 0.0f;
    #pragma unroll
    for (int k = 0; k < 4; k++) {
        float e = __expf(sc[k] - mx);
        sc[k] = e;
        lsum += e;
    }
    #pragma unroll
    for (int off = 32; off > 0; off >>= 1) lsum += __shfl_xor(lsum, off, 64);
    __syncthreads();                   // protect red reuse
    if ((tid & 63) == 0) red[tid >> 6] = lsum;
    __syncthreads();
    float inv = 1.0f / (red[0] + red[1] + red[2] + red[3]);

    float* arow = at + (size_t)bt * TT;
    #pragma unroll
    for (int k = 0; k < 4; k++) {
        arow[(k << 8) + tid] = sc[k] * inv;
    }
}

// Kernel 4: out[b] = at[b] (1024x1024) @ inputs[b] (1024x512), fp32 tiled GEMM.
// BM=BN=64, BK=32, 256 threads, 4x4 micro-tile per thread.
__global__ __launch_bounds__(256) void av_gemm_kernel(
    const float* __restrict__ at, const float* __restrict__ x, float* __restrict__ out) {
    __shared__ float At[64][36];      // +4 pad: rotates banks across rows, keeps 16B align
    __shared__ float Xt[32][64];
    int b = blockIdx.z;
    int tm = blockIdx.y << 6;
    int tn = blockIdx.x << 6;
    const float* A = at + (size_t)b * TT * TT;
    const float* X = x + (size_t)b * TT * DD;
    float* C = out + (size_t)b * TT * DD;
    int tid = threadIdx.x;
    int tx = tid & 15, ty = tid >> 4;

    float c[4][4] = {};
    for (int k0 = 0; k0 < TT; k0 += 32) {
        #pragma unroll
        for (int i = 0; i < 2; i++) {
            int f = tid + (i << 8);     // 0..511 float4 slots, 8 per row
            int r = f >> 3, c4 = (f & 7) << 2;
            float4 v = *(const float4*)(A + (size_t)(tm + r) * TT + k0 + c4);
            *(float4*)&At[r][c4] = v;
        }
        #pragma unroll
        for (int i = 0; i < 2; i++) {
            int f = tid + (i << 8);     // 16 float4 per row
            int r = f >> 4, c4 = (f & 15) << 2;
            float4 v = *(const float4*)(X + (size_t)(k0 + r) * DD + tn + c4);
            *(float4*)&Xt[r][c4] = v;
        }
        __syncthreads();
        #pragma unroll
        for (int k4 = 0; k4 < 8; k4++) {
            float4 a0 = *(const float4*)&At[(ty << 2) + 0][k4 << 2];
            float4 a1 = *(const float4*)&At[(ty << 2) + 1][k4 << 2];
            float4 a2 = *(const float4*)&At[(ty << 2) + 2][k4 << 2];
            float4 a3 = *(const float4*)&At[(ty << 2) + 3][k4 << 2];
            const float* av0 = (const float*)&a0;
            const float* av1 = (const float*)&a1;
            const float* av2 = (const float*)&a2;
            const float* av3 = (const float*)&a3;
            #pragma unroll
            for (int kk = 0; kk < 4; kk++) {
                float4 bb = *(const float4*)&Xt[(k4 << 2) + kk][tx << 2];
                c[0][0] = fmaf(av0[kk], bb.x, c[0][0]);
                c[0][1] = fmaf(av0[kk], bb.y, c[0][1]);
                c[0][2] = fmaf(av0[kk], bb.z, c[0][2]);
                c[0][3] = fmaf(av0[kk], bb.w, c[0][3]);
                c[1][0] = fmaf(av1[kk], bb.x, c[1][0]);
                c[1][1] = fmaf(av1[kk], bb.y, c[1][1]);
                c[1][2] = fmaf(av1[kk], bb.z, c[1][2]);
                c[1][3] = fmaf(av1[kk], bb.w, c[1][3]);
                c[2][0] = fmaf(av2[kk], bb.x, c[2][0]);
                c[2][1] = fmaf(av2[kk], bb.y, c[2][1]);
                c[2][2] = fmaf(av2[kk], bb.z, c[2][2]);
                c[2][3] = fmaf(av2[kk], bb.w, c[2][3]);
                c[3][0] = fmaf(av3[kk], bb.x, c[3][0]);
                c[3][1] = fmaf(av3[kk], bb.y, c[3][1]);
                c[3][2] = fmaf(av3[kk], bb.z, c[3][2]);
                c[3][3] = fmaf(av3[kk], bb.w, c[3][3]);
            }
        }
        __syncthreads();
    }
    #pragma unroll
    for (int i = 0; i < 4; i++) {
        float4 v = make_float4(c[i][0], c[i][1], c[i][2], c[i][3]);
        *(float4*)(C + (size_t)(tm + (ty << 2) + i) * DD + tn + (tx << 2)) = v;
    }
}

extern "C" void kernel_launch(void* const* d_in, const int* in_sizes, int n_in,
                              void* d_out, int out_size, void* d_ws, size_t ws_size,
                              hipStream_t stream) {
    const float* inputs = (const float*)d_in[0];   // (B,T,D)
    const float* ec     = (const float*)d_in[1];   // (B,M)
    const float* W1     = (const float*)d_in[2];   // (D,P)
    const float* b1     = (const float*)d_in[3];   // (P,)
    const float* W2     = (const float*)d_in[4];   // (D,P)
    const float* b2     = (const float*)d_in[5];   // (P,)
    const float* W3     = (const float*)d_in[6];   // (M,P)
    const float* b3     = (const float*)d_in[7];   // (P,)
    const float* wa_w   = (const float*)d_in[8];   // (P,)
    const float* wa_b   = (const float*)d_in[9];   // scalar
    float* out = (float*)d_out;                    // (B,T,D) fp32

    // Workspace layout (floats): w1h[262144] | w2h[262144] | w3e[256] | pad | at[4194304]
    float* ws  = (float*)d_ws;
    float* w1h = ws;
    float* w2h = ws + 262144;
    float* w3e = ws + 524288;
    float* at  = ws + 524800;   // 16B-aligned offset; total ~18.9 MB

    hipLaunchKernelGGL(proj_kernel, dim3(1024), dim3(256), 0, stream,
                       inputs, W1, b1, W2, b2, w1h, w2h);
    hipLaunchKernelGGL(ec_proj_kernel, dim3(1), dim3(256), 0, stream,
                       ec, W3, b3, w3e);
    hipLaunchKernelGGL(scores_kernel, dim3(BB * TT), dim3(256), 0, stream,
                       w1h, w2h, w3e, wa_w, wa_b, at);
    hipLaunchKernelGGL(av_gemm_kernel, dim3(DD / 64, TT / 64, BB), dim3(256), 0, stream,
                       at, inputs, out);
}